// Round 1
// baseline (616.830 us; speedup 1.0000x reference)
//
#include <hip/hip_runtime.h>
#include <hip/hip_bf16.h>

#define F_IN   128
#define F_HID  256
#define F_OUT  16

// ---------------------------------------------------------------------------
// Phase 1: degree histogram (in-degree of dst, excluding self loop)
// ---------------------------------------------------------------------------
__global__ __launch_bounds__(256) void count_deg_k(const int* __restrict__ ei,
                                                   int* __restrict__ deg,
                                                   int E) {
    int e = blockIdx.x * 256 + threadIdx.x;
    if (e >= E) return;
    int d = ei[E + e];
    atomicAdd(&deg[d], 1);
}

// dinv[i] = rsqrt(deg[i] + 1)   (+1 = self loop)
__global__ __launch_bounds__(256) void dinv_k(const int* __restrict__ deg,
                                              float* __restrict__ dinv,
                                              int N) {
    int i = blockIdx.x * 256 + threadIdx.x;
    if (i >= N) return;
    dinv[i] = rsqrtf((float)(deg[i] + 1));
}

// ---------------------------------------------------------------------------
// Phase 2: exclusive prefix sum of deg -> start[]   (3-kernel scan)
// ---------------------------------------------------------------------------
#define SCAN_B 1024

__global__ __launch_bounds__(SCAN_B) void scanA_k(const int* __restrict__ deg,
                                                  int* __restrict__ partials,
                                                  int N) {
    __shared__ int sm[SCAN_B];
    int tid = threadIdx.x;
    int idx = blockIdx.x * SCAN_B + tid;
    sm[tid] = (idx < N) ? deg[idx] : 0;
    __syncthreads();
    for (int s = SCAN_B / 2; s > 0; s >>= 1) {
        if (tid < s) sm[tid] += sm[tid + s];
        __syncthreads();
    }
    if (tid == 0) partials[blockIdx.x] = sm[0];
}

__global__ __launch_bounds__(128) void scanB_k(int* __restrict__ partials, int nb) {
    __shared__ int sm[128];
    int tid = threadIdx.x;
    if (tid < nb) sm[tid] = partials[tid];
    __syncthreads();
    if (tid == 0) {
        int run = 0;
        for (int i = 0; i < nb; ++i) { int t = sm[i]; sm[i] = run; run += t; }
    }
    __syncthreads();
    if (tid < nb) partials[tid] = sm[tid];
}

__global__ __launch_bounds__(SCAN_B) void scanC_k(const int* __restrict__ deg,
                                                  const int* __restrict__ partials,
                                                  int* __restrict__ start,
                                                  int N) {
    __shared__ int sm[SCAN_B];
    int tid = threadIdx.x;
    int idx = blockIdx.x * SCAN_B + tid;
    int v = (idx < N) ? deg[idx] : 0;
    sm[tid] = v;
    __syncthreads();
    // Hillis-Steele inclusive scan
    for (int off = 1; off < SCAN_B; off <<= 1) {
        int t = (tid >= off) ? sm[tid - off] : 0;
        __syncthreads();
        sm[tid] += t;
        __syncthreads();
    }
    if (idx < N) start[idx] = partials[blockIdx.x] + sm[tid] - v;  // exclusive
}

// ---------------------------------------------------------------------------
// Phase 3: scatter edges into CSR-by-dst (counting sort)
// ---------------------------------------------------------------------------
__global__ __launch_bounds__(256) void scatter_k(const int* __restrict__ ei,
                                                 const int* __restrict__ start,
                                                 int* __restrict__ cursor,
                                                 int* __restrict__ csr_src,
                                                 int E) {
    int e = blockIdx.x * 256 + threadIdx.x;
    if (e >= E) return;
    int s = ei[e];
    int d = ei[E + e];
    int pos = atomicAdd(&cursor[d], 1);
    csr_src[start[d] + pos] = s;
}

// ---------------------------------------------------------------------------
// Phase 4: layer-1 aggregation  agg1 = D^-1/2 (A+I) D^-1/2 x   (F=128)
// One wave per dst node; lane handles 2 feats (float2). No atomics.
// ---------------------------------------------------------------------------
__global__ __launch_bounds__(256) void agg1_k(const float* __restrict__ x,
                                              const float* __restrict__ dinv,
                                              const int* __restrict__ start,
                                              const int* __restrict__ deg,
                                              const int* __restrict__ csr_src,
                                              float* __restrict__ agg1,
                                              int N) {
    int wid = (blockIdx.x * 256 + threadIdx.x) >> 6;  // node id
    int lane = threadIdx.x & 63;
    if (wid >= N) return;
    const float2* x2 = (const float2*)x;
    float dv = dinv[wid];
    float2 acc = x2[(size_t)wid * 64 + lane];
    float sw = dv * dv;                    // self-loop norm
    acc.x *= sw; acc.y *= sw;
    int s0 = start[wid], cnt = deg[wid];
    for (int i = 0; i < cnt; ++i) {
        int s = csr_src[s0 + i];           // wave-uniform
        float nm = dinv[s] * dv;
        float2 v = x2[(size_t)s * 64 + lane];
        acc.x += v.x * nm;
        acc.y += v.y * nm;
    }
    ((float2*)agg1)[(size_t)wid * 64 + lane] = acc;
}

// ---------------------------------------------------------------------------
// Phase 5: GEMM1 + bias + ReLU:  h1 = relu(agg1 @ W1 + b1)
// [N,128] @ [128,256]. fp32 vector (no fp32 MFMA). 64x64 tile, 4x4/thread.
// ---------------------------------------------------------------------------
#define BM 64
#define BN 64
#define BK 16

__global__ __launch_bounds__(256) void gemm1_relu_k(const float* __restrict__ A,
                                                    const float* __restrict__ B,
                                                    const float* __restrict__ bias,
                                                    float* __restrict__ C,
                                                    int M) {
    __shared__ float As[BK][BM + 4];   // [k][m], pad 4 -> 272B rows (16B aligned)
    __shared__ float Bs[BK][BN + 4];
    int m0 = blockIdx.x * BM;
    int n0 = blockIdx.y * BN;
    int tid = threadIdx.x;
    int tx = tid & 15, ty = tid >> 4;
    float acc[4][4] = {};

    for (int k0 = 0; k0 < F_IN; k0 += BK) {
        {   // A tile: 64 rows x 16 k; thread: row=tid>>2, k=(tid&3)*4
            int r = tid >> 2, kk = (tid & 3) * 4;
            int row = m0 + r; if (row >= M) row = M - 1;
            float4 av = *reinterpret_cast<const float4*>(A + (size_t)row * F_IN + k0 + kk);
            As[kk + 0][r] = av.x; As[kk + 1][r] = av.y;
            As[kk + 2][r] = av.z; As[kk + 3][r] = av.w;
        }
        {   // B tile: 16 k x 64 cols; thread: k=tid>>4, n=(tid&15)*4
            int k = tid >> 4, nn = (tid & 15) * 4;
            float4 bv = *reinterpret_cast<const float4*>(B + (size_t)(k0 + k) * F_HID + n0 + nn);
            *reinterpret_cast<float4*>(&Bs[k][nn]) = bv;
        }
        __syncthreads();
        #pragma unroll
        for (int kk = 0; kk < BK; ++kk) {
            float4 a = *reinterpret_cast<const float4*>(&As[kk][ty * 4]);
            float4 b = *reinterpret_cast<const float4*>(&Bs[kk][tx * 4]);
            acc[0][0] += a.x * b.x; acc[0][1] += a.x * b.y; acc[0][2] += a.x * b.z; acc[0][3] += a.x * b.w;
            acc[1][0] += a.y * b.x; acc[1][1] += a.y * b.y; acc[1][2] += a.y * b.z; acc[1][3] += a.y * b.w;
            acc[2][0] += a.z * b.x; acc[2][1] += a.z * b.y; acc[2][2] += a.z * b.z; acc[2][3] += a.z * b.w;
            acc[3][0] += a.w * b.x; acc[3][1] += a.w * b.y; acc[3][2] += a.w * b.z; acc[3][3] += a.w * b.w;
        }
        __syncthreads();
    }
    #pragma unroll
    for (int i = 0; i < 4; ++i) {
        int row = m0 + ty * 4 + i;
        if (row < M) {
            float4 bi = *reinterpret_cast<const float4*>(bias + n0 + tx * 4);
            float4 o;
            o.x = fmaxf(acc[i][0] + bi.x, 0.f);
            o.y = fmaxf(acc[i][1] + bi.y, 0.f);
            o.z = fmaxf(acc[i][2] + bi.z, 0.f);
            o.w = fmaxf(acc[i][3] + bi.w, 0.f);
            *reinterpret_cast<float4*>(C + (size_t)row * F_HID + n0 + tx * 4) = o;
        }
    }
}

// ---------------------------------------------------------------------------
// Phase 6: GEMM2: h2pre = h1 @ W2   [N,256]@[256,16]. W2 lives in LDS.
// ---------------------------------------------------------------------------
__global__ __launch_bounds__(256) void gemm2_k(const float* __restrict__ h1,
                                               const float* __restrict__ W2,
                                               float* __restrict__ h2,
                                               int N) {
    __shared__ float w2s[F_HID * F_OUT];      // [k][j], 16 KB
    __shared__ float hs[16][F_HID + 4];       // 16 nodes x 256 (+pad)
    int tid = threadIdx.x;
    const float4* wg = (const float4*)W2;
    float4* ws4 = (float4*)w2s;
    for (int i = tid; i < F_HID * F_OUT / 4; i += 256) ws4[i] = wg[i];
    int n0 = blockIdx.x * 16;
    const float4* hg = (const float4*)(h1 + (size_t)n0 * F_HID);
    for (int i = tid; i < 16 * F_HID / 4; i += 256) {
        int r = i >> 6, c = i & 63;
        *reinterpret_cast<float4*>(&hs[r][c * 4]) = hg[i];
    }
    __syncthreads();
    int ln = tid >> 4, j = tid & 15;
    float acc = 0.f;
    #pragma unroll 8
    for (int k = 0; k < F_HID; ++k) acc += hs[ln][k] * w2s[k * F_OUT + j];
    h2[(size_t)(n0 + ln) * F_OUT + j] = acc;
}

// ---------------------------------------------------------------------------
// Phase 7: layer-2 aggregation (F=16) fused with bias + log_softmax.
// 16 lanes per node; shfl reductions within the 16-lane group.
// ---------------------------------------------------------------------------
__global__ __launch_bounds__(256) void agg2_softmax_k(const float* __restrict__ h2,
                                                      const float* __restrict__ dinv,
                                                      const int* __restrict__ start,
                                                      const int* __restrict__ deg,
                                                      const int* __restrict__ csr_src,
                                                      const float* __restrict__ b2,
                                                      float* __restrict__ out,
                                                      int N) {
    int idx = blockIdx.x * 256 + threadIdx.x;
    int n = idx >> 4, j = idx & 15;
    if (n >= N) return;
    float dv = dinv[n];
    float acc = h2[(size_t)n * F_OUT + j] * dv * dv;   // self loop
    int s0 = start[n], cnt = deg[n];
    for (int i = 0; i < cnt; ++i) {
        int s = csr_src[s0 + i];
        float nm = dinv[s] * dv;
        acc += h2[(size_t)s * F_OUT + j] * nm;
    }
    acc += b2[j];
    float m = acc;
    #pragma unroll
    for (int o = 8; o >= 1; o >>= 1) m = fmaxf(m, __shfl_xor(m, o, 16));
    float e = expf(acc - m);
    float ssum = e;
    #pragma unroll
    for (int o = 8; o >= 1; o >>= 1) ssum += __shfl_xor(ssum, o, 16);
    out[(size_t)n * F_OUT + j] = acc - m - logf(ssum);
}

// ---------------------------------------------------------------------------
extern "C" void kernel_launch(void* const* d_in, const int* in_sizes, int n_in,
                              void* d_out, int out_size, void* d_ws, size_t ws_size,
                              hipStream_t stream) {
    const float* x  = (const float*)d_in[0];
    const int*   ei = (const int*)d_in[1];     // int32 per harness convention
    const float* W1 = (const float*)d_in[2];
    const float* b1 = (const float*)d_in[3];
    const float* W2 = (const float*)d_in[4];
    const float* b2 = (const float*)d_in[5];
    float* out = (float*)d_out;

    const int N = in_sizes[0] / F_IN;
    const int E = in_sizes[1] / 2;

    // ---- workspace layout (bytes) ----
    const size_t P = ((size_t)N * 4 + 4095) & ~(size_t)4095;   // padded N-int array
    char* ws = (char*)d_ws;
    int*   deg      = (int*)(ws + 0 * P);
    int*   cursor   = (int*)(ws + 1 * P);
    float* dinv     = (float*)(ws + 2 * P);
    int*   start    = (int*)(ws + 3 * P);
    int*   partials = (int*)(ws + 4 * P);
    char*  base     = ws + 4 * P + 4096;
    int*   csr_src  = (int*)base;
    const size_t csrB = ((size_t)E * 4 + 4095) & ~(size_t)4095;
    float* agg1     = (float*)(base + csrB);
    const size_t agg1B = (size_t)N * F_IN * 4;
    float* h1       = (float*)(base + csrB + agg1B);
    float* h2pre    = agg1;   // agg1 dead after gemm1 -> alias

    // zero deg + cursor (contiguous)
    hipMemsetAsync(ws, 0, 2 * P, stream);

    const int nbE = (E + 255) / 256;
    const int nbN = (N + 255) / 256;
    const int NB  = (N + SCAN_B - 1) / SCAN_B;

    count_deg_k<<<nbE, 256, 0, stream>>>(ei, deg, E);
    dinv_k<<<nbN, 256, 0, stream>>>(deg, dinv, N);
    scanA_k<<<NB, SCAN_B, 0, stream>>>(deg, partials, N);
    scanB_k<<<1, 128, 0, stream>>>(partials, NB);
    scanC_k<<<NB, SCAN_B, 0, stream>>>(deg, partials, start, N);
    scatter_k<<<nbE, 256, 0, stream>>>(ei, start, cursor, csr_src, E);

    // layer 1: aggregate-first (F=128), then GEMM+ReLU
    agg1_k<<<(N + 3) / 4, 256, 0, stream>>>(x, dinv, start, deg, csr_src, agg1, N);
    dim3 g1((N + BM - 1) / BM, F_HID / BN);
    gemm1_relu_k<<<g1, 256, 0, stream>>>(agg1, W1, b1, h1, N);

    // layer 2: transform-first (F=16), aggregate fused with bias+log_softmax
    gemm2_k<<<N / 16, 256, 0, stream>>>(h1, W2, h2pre, N);
    agg2_softmax_k<<<(N * 16 + 255) / 256, 256, 0, stream>>>(h2pre, dinv, start, deg,
                                                             csr_src, b2, out, N);
}

// Round 3
// 611.051 us; speedup vs baseline: 1.0095x; 1.0095x over previous
//
#include <hip/hip_runtime.h>
#include <hip/hip_bf16.h>

#define F_IN   128
#define F_HID  256
#define F_OUT  16

// ---------------------------------------------------------------------------
// Phase 1: degree histogram (in-degree of dst, excluding self loop)
// ---------------------------------------------------------------------------
__global__ __launch_bounds__(256) void count_deg_k(const int* __restrict__ ei,
                                                   int* __restrict__ deg,
                                                   int E) {
    int e = blockIdx.x * 256 + threadIdx.x;
    if (e >= E) return;
    int d = ei[E + e];
    atomicAdd(&deg[d], 1);
}

// dinv[i] = rsqrt(deg[i] + 1)   (+1 = self loop)
__global__ __launch_bounds__(256) void dinv_k(const int* __restrict__ deg,
                                              float* __restrict__ dinv,
                                              int N) {
    int i = blockIdx.x * 256 + threadIdx.x;
    if (i >= N) return;
    dinv[i] = rsqrtf((float)(deg[i] + 1));
}

// ---------------------------------------------------------------------------
// Phase 2: exclusive prefix sum of deg -> start[]   (3-kernel scan)
// ---------------------------------------------------------------------------
#define SCAN_B 1024

__global__ __launch_bounds__(SCAN_B) void scanA_k(const int* __restrict__ deg,
                                                  int* __restrict__ partials,
                                                  int N) {
    __shared__ int sm[SCAN_B];
    int tid = threadIdx.x;
    int idx = blockIdx.x * SCAN_B + tid;
    sm[tid] = (idx < N) ? deg[idx] : 0;
    __syncthreads();
    for (int s = SCAN_B / 2; s > 0; s >>= 1) {
        if (tid < s) sm[tid] += sm[tid + s];
        __syncthreads();
    }
    if (tid == 0) partials[blockIdx.x] = sm[0];
}

__global__ __launch_bounds__(128) void scanB_k(int* __restrict__ partials, int nb) {
    __shared__ int sm[128];
    int tid = threadIdx.x;
    if (tid < nb) sm[tid] = partials[tid];
    __syncthreads();
    if (tid == 0) {
        int run = 0;
        for (int i = 0; i < nb; ++i) { int t = sm[i]; sm[i] = run; run += t; }
    }
    __syncthreads();
    if (tid < nb) partials[tid] = sm[tid];
}

// also pre-fills cursor[] with the same exclusive-scan value (saves a
// start[] gather + memset in scatter_k)
__global__ __launch_bounds__(SCAN_B) void scanC_k(const int* __restrict__ deg,
                                                  const int* __restrict__ partials,
                                                  int* __restrict__ start,
                                                  int* __restrict__ cursor,
                                                  int N) {
    __shared__ int sm[SCAN_B];
    int tid = threadIdx.x;
    int idx = blockIdx.x * SCAN_B + tid;
    int v = (idx < N) ? deg[idx] : 0;
    sm[tid] = v;
    __syncthreads();
    // Hillis-Steele inclusive scan
    for (int off = 1; off < SCAN_B; off <<= 1) {
        int t = (tid >= off) ? sm[tid - off] : 0;
        __syncthreads();
        sm[tid] += t;
        __syncthreads();
    }
    if (idx < N) {
        int excl = partials[blockIdx.x] + sm[tid] - v;
        start[idx]  = excl;
        cursor[idx] = excl;
    }
}

// ---------------------------------------------------------------------------
// Phase 3: scatter edges into CSR-by-dst (counting sort). cursor pre-filled
// with start, so atomicAdd returns the absolute slot.
// ---------------------------------------------------------------------------
__global__ __launch_bounds__(256) void scatter_k(const int* __restrict__ ei,
                                                 int* __restrict__ cursor,
                                                 int* __restrict__ csr_src,
                                                 int E) {
    int e = blockIdx.x * 256 + threadIdx.x;
    if (e >= E) return;
    int s = ei[e];
    int d = ei[E + e];
    int pos = atomicAdd(&cursor[d], 1);
    csr_src[pos] = s;
}

// ---------------------------------------------------------------------------
// Phase 4: layer-1 aggregation  agg1 = D^-1/2 (A+I) D^-1/2 x   (F=128)
// One wave per dst node. 32 lanes cover one 512B row as float4; the two
// wave-halves process even/odd edges; manual 4x unroll -> 8 gathers in
// flight per wave (latency-bound fix: MLP, not bytes).
// ---------------------------------------------------------------------------
__global__ __launch_bounds__(256) void agg1_k(const float* __restrict__ x,
                                              const float* __restrict__ dinv,
                                              const int* __restrict__ start,
                                              const int* __restrict__ deg,
                                              const int* __restrict__ csr_src,
                                              float* __restrict__ agg1,
                                              int N) {
    int wid = (blockIdx.x * 256 + threadIdx.x) >> 6;  // node id
    if (wid >= N) return;
    int lane = threadIdx.x & 63;
    int h  = lane >> 5;     // which edge of the pair this half handles
    int li = lane & 31;     // float4 slot within the 128-float row
    const float4* x4 = (const float4*)x;

    float dv = dinv[wid];
    float sw = (h == 0) ? dv * dv : 0.f;     // self-loop only in half 0
    float4 self = x4[(size_t)wid * 32 + li];
    float4 acc = { self.x * sw, self.y * sw, self.z * sw, self.w * sw };

    int s0 = start[wid], cnt = deg[wid];
    int npair = (cnt + 1) >> 1;              // half h handles edge 2p+h

    for (int p = 0; p < npair; p += 4) {
        int   s[4];
        float nm[4];
        float4 v[4];
        #pragma unroll
        for (int u = 0; u < 4; ++u) {
            int e = ((p + u) << 1) + h;
            s[u] = (e < cnt) ? csr_src[s0 + e] : wid;   // clamp: safe addr
        }
        #pragma unroll
        for (int u = 0; u < 4; ++u) {
            int e = ((p + u) << 1) + h;
            nm[u] = (e < cnt) ? dinv[s[u]] * dv : 0.f;  // mask: zero weight
        }
        #pragma unroll
        for (int u = 0; u < 4; ++u)
            v[u] = x4[(size_t)s[u] * 32 + li];
        #pragma unroll
        for (int u = 0; u < 4; ++u) {
            acc.x = fmaf(v[u].x, nm[u], acc.x);
            acc.y = fmaf(v[u].y, nm[u], acc.y);
            acc.z = fmaf(v[u].z, nm[u], acc.z);
            acc.w = fmaf(v[u].w, nm[u], acc.w);
        }
    }
    // combine the two halves: half 1's partial lives in lanes 32..63
    acc.x += __shfl_xor(acc.x, 32);
    acc.y += __shfl_xor(acc.y, 32);
    acc.z += __shfl_xor(acc.z, 32);
    acc.w += __shfl_xor(acc.w, 32);
    if (h == 0)
        ((float4*)agg1)[(size_t)wid * 32 + li] = acc;
}

// ---------------------------------------------------------------------------
// Phase 5: GEMM1 + bias + ReLU:  h1 = relu(agg1 @ W1 + b1)
// [N,128] @ [128,256]. fp32 vector (no fp32 MFMA). 64x64 tile, 4x4/thread.
// ---------------------------------------------------------------------------
#define BM 64
#define BN 64
#define BK 16

__global__ __launch_bounds__(256) void gemm1_relu_k(const float* __restrict__ A,
                                                    const float* __restrict__ B,
                                                    const float* __restrict__ bias,
                                                    float* __restrict__ C,
                                                    int M) {
    __shared__ float As[BK][BM + 4];   // [k][m]
    __shared__ float Bs[BK][BN + 4];
    int m0 = blockIdx.x * BM;
    int n0 = blockIdx.y * BN;
    int tid = threadIdx.x;
    int tx = tid & 15, ty = tid >> 4;
    float acc[4][4] = {};

    for (int k0 = 0; k0 < F_IN; k0 += BK) {
        {   // A tile: 64 rows x 16 k; thread: row=tid>>2, k=(tid&3)*4
            int r = tid >> 2, kk = (tid & 3) * 4;
            int row = m0 + r; if (row >= M) row = M - 1;
            float4 av = *reinterpret_cast<const float4*>(A + (size_t)row * F_IN + k0 + kk);
            As[kk + 0][r] = av.x; As[kk + 1][r] = av.y;
            As[kk + 2][r] = av.z; As[kk + 3][r] = av.w;
        }
        {   // B tile: 16 k x 64 cols; thread: k=tid>>4, n=(tid&15)*4
            int k = tid >> 4, nn = (tid & 15) * 4;
            float4 bv = *reinterpret_cast<const float4*>(B + (size_t)(k0 + k) * F_HID + n0 + nn);
            *reinterpret_cast<float4*>(&Bs[k][nn]) = bv;
        }
        __syncthreads();
        #pragma unroll
        for (int kk = 0; kk < BK; ++kk) {
            float4 a = *reinterpret_cast<const float4*>(&As[kk][ty * 4]);
            float4 b = *reinterpret_cast<const float4*>(&Bs[kk][tx * 4]);
            acc[0][0] += a.x * b.x; acc[0][1] += a.x * b.y; acc[0][2] += a.x * b.z; acc[0][3] += a.x * b.w;
            acc[1][0] += a.y * b.x; acc[1][1] += a.y * b.y; acc[1][2] += a.y * b.z; acc[1][3] += a.y * b.w;
            acc[2][0] += a.z * b.x; acc[2][1] += a.z * b.y; acc[2][2] += a.z * b.z; acc[2][3] += a.z * b.w;
            acc[3][0] += a.w * b.x; acc[3][1] += a.w * b.y; acc[3][2] += a.w * b.z; acc[3][3] += a.w * b.w;
        }
        __syncthreads();
    }
    #pragma unroll
    for (int i = 0; i < 4; ++i) {
        int row = m0 + ty * 4 + i;
        if (row < M) {
            float4 bi = *reinterpret_cast<const float4*>(bias + n0 + tx * 4);
            float4 o;
            o.x = fmaxf(acc[i][0] + bi.x, 0.f);
            o.y = fmaxf(acc[i][1] + bi.y, 0.f);
            o.z = fmaxf(acc[i][2] + bi.z, 0.f);
            o.w = fmaxf(acc[i][3] + bi.w, 0.f);
            *reinterpret_cast<float4*>(C + (size_t)row * F_HID + n0 + tx * 4) = o;
        }
    }
}

// ---------------------------------------------------------------------------
// Phase 6: GEMM2: h2pre = h1 @ W2   [N,256]@[256,16]. W2 lives in LDS.
// ---------------------------------------------------------------------------
__global__ __launch_bounds__(256) void gemm2_k(const float* __restrict__ h1,
                                               const float* __restrict__ W2,
                                               float* __restrict__ h2,
                                               int N) {
    __shared__ float w2s[F_HID * F_OUT];      // [k][j], 16 KB
    __shared__ float hs[16][F_HID + 4];       // 16 nodes x 256 (+pad)
    int tid = threadIdx.x;
    const float4* wg = (const float4*)W2;
    float4* ws4 = (float4*)w2s;
    for (int i = tid; i < F_HID * F_OUT / 4; i += 256) ws4[i] = wg[i];
    int n0 = blockIdx.x * 16;
    const float4* hg = (const float4*)(h1 + (size_t)n0 * F_HID);
    for (int i = tid; i < 16 * F_HID / 4; i += 256) {
        int r = i >> 6, c = i & 63;
        *reinterpret_cast<float4*>(&hs[r][c * 4]) = hg[i];
    }
    __syncthreads();
    int ln = tid >> 4, j = tid & 15;
    float acc = 0.f;
    #pragma unroll 8
    for (int k = 0; k < F_HID; ++k) acc += hs[ln][k] * w2s[k * F_OUT + j];
    h2[(size_t)(n0 + ln) * F_OUT + j] = acc;
}

// ---------------------------------------------------------------------------
// Phase 7: layer-2 aggregation (F=16) fused with bias + log_softmax.
// One wave per node; 4 lanes cover one 64B row as float4 -> 16 edges in
// flight per loop iteration. Shuffle-reduce, then softmax in-register.
// ---------------------------------------------------------------------------
__global__ __launch_bounds__(256) void agg2_softmax_k(const float* __restrict__ h2,
                                                      const float* __restrict__ dinv,
                                                      const int* __restrict__ start,
                                                      const int* __restrict__ deg,
                                                      const int* __restrict__ csr_src,
                                                      const float* __restrict__ b2,
                                                      float* __restrict__ out,
                                                      int N) {
    int wid = (blockIdx.x * 256 + threadIdx.x) >> 6;
    if (wid >= N) return;
    int lane = threadIdx.x & 63;
    int g  = lane >> 2;     // edge slot 0..15
    int j4 = lane & 3;      // float4 slot within the 16-float row
    const float4* h4 = (const float4*)h2;

    float dv = dinv[wid];
    float sw = (g == 0) ? dv * dv : 0.f;     // self loop counted once
    float4 self = h4[(size_t)wid * 4 + j4];
    float4 acc = { self.x * sw, self.y * sw, self.z * sw, self.w * sw };

    int s0 = start[wid], cnt = deg[wid];
    for (int p = 0; p < cnt; p += 16) {
        int e = p + g;
        bool ok = e < cnt;
        int   s  = ok ? csr_src[s0 + e] : wid;
        float nm = ok ? dinv[s] * dv : 0.f;
        float4 v = h4[(size_t)s * 4 + j4];
        acc.x = fmaf(v.x, nm, acc.x);
        acc.y = fmaf(v.y, nm, acc.y);
        acc.z = fmaf(v.z, nm, acc.z);
        acc.w = fmaf(v.w, nm, acc.w);
    }
    // sum over the 16 edge slots (lane bits 2..5)
    #pragma unroll
    for (int o = 4; o <= 32; o <<= 1) {
        acc.x += __shfl_xor(acc.x, o);
        acc.y += __shfl_xor(acc.y, o);
        acc.z += __shfl_xor(acc.z, o);
        acc.w += __shfl_xor(acc.w, o);
    }
    float4 bb = ((const float4*)b2)[j4];
    acc.x += bb.x; acc.y += bb.y; acc.z += bb.z; acc.w += bb.w;

    // log-softmax over the 16 outputs (4 per lane x lane bits 0..1)
    float m = fmaxf(fmaxf(acc.x, acc.y), fmaxf(acc.z, acc.w));
    m = fmaxf(m, __shfl_xor(m, 1));
    m = fmaxf(m, __shfl_xor(m, 2));
    float es = expf(acc.x - m) + expf(acc.y - m) + expf(acc.z - m) + expf(acc.w - m);
    es += __shfl_xor(es, 1);
    es += __shfl_xor(es, 2);
    float lse = m + logf(es);

    if (g == 0) {
        float4 o4 = { acc.x - lse, acc.y - lse, acc.z - lse, acc.w - lse };
        ((float4*)out)[(size_t)wid * 4 + j4] = o4;
    }
}

// ---------------------------------------------------------------------------
extern "C" void kernel_launch(void* const* d_in, const int* in_sizes, int n_in,
                              void* d_out, int out_size, void* d_ws, size_t ws_size,
                              hipStream_t stream) {
    const float* x  = (const float*)d_in[0];
    const int*   ei = (const int*)d_in[1];     // int32 per harness convention
    const float* W1 = (const float*)d_in[2];
    const float* b1 = (const float*)d_in[3];
    const float* W2 = (const float*)d_in[4];
    const float* b2 = (const float*)d_in[5];
    float* out = (float*)d_out;

    const int N = in_sizes[0] / F_IN;
    const int E = in_sizes[1] / 2;

    // ---- workspace layout (bytes) ----
    const size_t P = ((size_t)N * 4 + 4095) & ~(size_t)4095;   // padded N-int array
    char* ws = (char*)d_ws;
    int*   deg      = (int*)(ws + 0 * P);
    int*   cursor   = (int*)(ws + 1 * P);
    float* dinv     = (float*)(ws + 2 * P);
    int*   start    = (int*)(ws + 3 * P);
    int*   partials = (int*)(ws + 4 * P);
    char*  base     = ws + 4 * P + 4096;
    int*   csr_src  = (int*)base;
    const size_t csrB = ((size_t)E * 4 + 4095) & ~(size_t)4095;
    float* agg1     = (float*)(base + csrB);
    const size_t agg1B = (size_t)N * F_IN * 4;
    float* h1       = (float*)(base + csrB + agg1B);
    float* h2pre    = agg1;   // agg1 dead after gemm1 -> alias

    // zero deg only (cursor is pre-filled by scanC)
    hipMemsetAsync(deg, 0, (size_t)N * 4, stream);

    const int nbE = (E + 255) / 256;
    const int nbN = (N + 255) / 256;
    const int NB  = (N + SCAN_B - 1) / SCAN_B;

    count_deg_k<<<nbE, 256, 0, stream>>>(ei, deg, E);
    dinv_k<<<nbN, 256, 0, stream>>>(deg, dinv, N);
    scanA_k<<<NB, SCAN_B, 0, stream>>>(deg, partials, N);
    scanB_k<<<1, 128, 0, stream>>>(partials, NB);
    scanC_k<<<NB, SCAN_B, 0, stream>>>(deg, partials, start, cursor, N);
    scatter_k<<<nbE, 256, 0, stream>>>(ei, cursor, csr_src, E);

    // layer 1: aggregate-first (F=128), then GEMM+ReLU
    agg1_k<<<(N + 3) / 4, 256, 0, stream>>>(x, dinv, start, deg, csr_src, agg1, N);
    dim3 g1((N + BM - 1) / BM, F_HID / BN);
    gemm1_relu_k<<<g1, 256, 0, stream>>>(agg1, W1, b1, h1, N);

    // layer 2: transform-first (F=16), aggregate fused with bias+log_softmax
    gemm2_k<<<N / 16, 256, 0, stream>>>(h1, W2, h2pre, N);
    agg2_softmax_k<<<(N + 3) / 4, 256, 0, stream>>>(h2pre, dinv, start, deg,
                                                    csr_src, b2, out, N);
}

// Round 7
// 477.696 us; speedup vs baseline: 1.2913x; 1.2792x over previous
//
#include <hip/hip_runtime.h>
#include <hip/hip_bf16.h>

#define F_IN   128
#define F_HID  256
#define F_OUT  16
#define NCH    256     // edge chunks (must stay 256: colscan_k assumes it)
#define MAXBUK 1600    // buckets of 64 dsts; supports N <= 102400

// ---------------------------------------------------------------------------
// K1: per-chunk bucket histogram (LDS atomics only) -> M[chunk][bucket]
// ---------------------------------------------------------------------------
__global__ __launch_bounds__(256) void hist_k(const int* __restrict__ ei,
                                              int* __restrict__ M,
                                              int E, int cpe, int nbuk) {
    __shared__ int h[MAXBUK];
    int tid = threadIdx.x, blk = blockIdx.x;
    for (int b = tid; b < nbuk; b += 256) h[b] = 0;
    __syncthreads();
    int e0 = blk * cpe;
    for (int i = tid; i < cpe; i += 256) {
        int e = e0 + i;
        if (e < E) atomicAdd(&h[ei[E + e] >> 6], 1);
    }
    __syncthreads();
    for (int b = tid; b < nbuk; b += 256) M[(size_t)blk * nbuk + b] = h[b];
}

// ---------------------------------------------------------------------------
// K2: per-bucket exclusive scan over the 256 chunks (one wave per bucket),
// in place; bucket totals out.
// ---------------------------------------------------------------------------
__global__ __launch_bounds__(64) void colscan_k(int* __restrict__ M,
                                                int* __restrict__ totals,
                                                int nbuk) {
    int b = blockIdx.x, l = threadIdx.x;
    int v[4], s = 0;
    #pragma unroll
    for (int u = 0; u < 4; ++u) { v[u] = M[(size_t)(l * 4 + u) * nbuk + b]; s += v[u]; }
    int incl = s;
    #pragma unroll
    for (int o = 1; o < 64; o <<= 1) { int t = __shfl_up(incl, o); if (l >= o) incl += t; }
    int run = incl - s;                       // exclusive over chunks
    #pragma unroll
    for (int u = 0; u < 4; ++u) { M[(size_t)(l * 4 + u) * nbuk + b] = run; run += v[u]; }
    if (l == 63) totals[b] = incl;
}

// ---------------------------------------------------------------------------
// K3: exclusive scan of bucket totals -> base[]   (single block, 2 elems/thr)
// ---------------------------------------------------------------------------
__global__ __launch_bounds__(1024) void base_k(const int* __restrict__ totals,
                                               int* __restrict__ base, int nbuk) {
    __shared__ int sm[1024];
    int t = threadIdx.x;
    int v0 = (2 * t     < nbuk) ? totals[2 * t]     : 0;
    int v1 = (2 * t + 1 < nbuk) ? totals[2 * t + 1] : 0;
    int p = v0 + v1;
    sm[t] = p;
    __syncthreads();
    for (int o = 1; o < 1024; o <<= 1) {
        int x = (t >= o) ? sm[t - o] : 0;
        __syncthreads();
        sm[t] += x;
        __syncthreads();
    }
    int excl = sm[t] - p;
    if (2 * t     < nbuk) base[2 * t]     = excl;
    if (2 * t + 1 < nbuk) base[2 * t + 1] = excl + v0;
}

// ---------------------------------------------------------------------------
// K4: scatter (src,dst) pairs into bucket regions. Cursors live in LDS,
// pre-offset by base + this chunk's exclusive prefix -> zero global atomics.
// ---------------------------------------------------------------------------
__global__ __launch_bounds__(256) void bscatter_k(const int* __restrict__ ei,
                                                  const int* __restrict__ M,
                                                  const int* __restrict__ base,
                                                  int2* __restrict__ tmp,
                                                  int E, int cpe, int nbuk) {
    __shared__ int cur[MAXBUK];
    int tid = threadIdx.x, blk = blockIdx.x;
    for (int b = tid; b < nbuk; b += 256)
        cur[b] = base[b] + M[(size_t)blk * nbuk + b];
    __syncthreads();
    int e0 = blk * cpe;
    for (int i = tid; i < cpe; i += 256) {
        int e = e0 + i;
        if (e < E) {
            int s = ei[e], d = ei[E + e];
            int slot = atomicAdd(&cur[d >> 6], 1);     // LDS atomic
            tmp[slot] = make_int2(s, d);
        }
    }
}

// ---------------------------------------------------------------------------
// K5: finalize one bucket (64 dsts): count per dst, scan, rank-scatter to
// csr_src; emit deg/start/dinv; fused xs = x * dinv row scaling.
// ---------------------------------------------------------------------------
__global__ __launch_bounds__(256) void fin_k(const int2* __restrict__ tmp,
                                             const int* __restrict__ base,
                                             const int* __restrict__ totals,
                                             const float* __restrict__ x,
                                             int* __restrict__ csr_src,
                                             int* __restrict__ start,
                                             int* __restrict__ deg,
                                             float* __restrict__ dinv,
                                             float* __restrict__ xs,
                                             int N) {
    __shared__ int dcnt[64], dcur[64];
    __shared__ float sdv[64];
    int b = blockIdx.x, tid = threadIdx.x;
    int bb = base[b], cnt = totals[b];
    if (tid < 64) dcnt[tid] = 0;
    __syncthreads();
    for (int i = tid; i < cnt; i += 256)
        atomicAdd(&dcnt[tmp[bb + i].y & 63], 1);
    __syncthreads();
    if (tid < 64) {                                    // wave 0: scan 64 counts
        int l = tid, v = dcnt[l];
        int incl = v;
        #pragma unroll
        for (int o = 1; o < 64; o <<= 1) { int t2 = __shfl_up(incl, o); if (l >= o) incl += t2; }
        int excl = incl - v;
        dcur[l] = excl;
        float dv = rsqrtf((float)v + 1.f);
        sdv[l] = dv;
        int d = b * 64 + l;
        if (d < N) { deg[d] = v; start[d] = bb + excl; dinv[d] = dv; }
    }
    __syncthreads();
    for (int i = tid; i < cnt; i += 256) {             // rank & scatter src
        int2 p = tmp[bb + i];
        int r = atomicAdd(&dcur[p.y & 63], 1);
        csr_src[bb + r] = p.x;
    }
    // fused: xs rows for this bucket's nodes (coalesced float4)
    int d0 = b * 64;
    int nn = min(64, N - d0);
    const float4* x4 = (const float4*)x;
    float4* xs4 = (float4*)xs;
    for (int i = tid; i < nn * 32; i += 256) {
        int l = i >> 5;
        float dv = sdv[l];
        size_t idx = (size_t)(d0 + l) * 32 + (i & 31);
        float4 vv = x4[idx];
        vv.x *= dv; vv.y *= dv; vv.z *= dv; vv.w *= dv;
        xs4[idx] = vv;
    }
}

// ---------------------------------------------------------------------------
// agg1 = dinv[d] * ( sum_{s in nbrs} xs[s] + xs[d] )    (xs already * dinv[s])
// One wave per dst; 32 lanes x float4 = one 512B row; even/odd edge halves,
// 4x unroll -> 8 row-gathers in flight; NO per-edge dinv gather.
// ---------------------------------------------------------------------------
__global__ __launch_bounds__(256) void agg1_k(const float* __restrict__ xs,
                                              const float* __restrict__ dinv,
                                              const int* __restrict__ start,
                                              const int* __restrict__ deg,
                                              const int* __restrict__ csr_src,
                                              float* __restrict__ agg1,
                                              int N) {
    int wid = (blockIdx.x * 256 + threadIdx.x) >> 6;
    if (wid >= N) return;
    int lane = threadIdx.x & 63;
    int h  = lane >> 5;
    int li = lane & 31;
    const float4* x4 = (const float4*)xs;

    float4 self = x4[(size_t)wid * 32 + li];
    float sw = (h == 0) ? 1.f : 0.f;
    float4 acc = { self.x * sw, self.y * sw, self.z * sw, self.w * sw };

    int s0 = start[wid], cnt = deg[wid];
    int npair = (cnt + 1) >> 1;

    for (int p = 0; p < npair; p += 4) {
        int s[4]; float nm[4]; float4 v[4];
        #pragma unroll
        for (int u = 0; u < 4; ++u) {
            int e = ((p + u) << 1) + h;
            s[u]  = (e < cnt) ? csr_src[s0 + e] : wid;
            nm[u] = (e < cnt) ? 1.f : 0.f;
        }
        #pragma unroll
        for (int u = 0; u < 4; ++u)
            v[u] = x4[(size_t)s[u] * 32 + li];
        #pragma unroll
        for (int u = 0; u < 4; ++u) {
            acc.x = fmaf(v[u].x, nm[u], acc.x);
            acc.y = fmaf(v[u].y, nm[u], acc.y);
            acc.z = fmaf(v[u].z, nm[u], acc.z);
            acc.w = fmaf(v[u].w, nm[u], acc.w);
        }
    }
    acc.x += __shfl_xor(acc.x, 32);
    acc.y += __shfl_xor(acc.y, 32);
    acc.z += __shfl_xor(acc.z, 32);
    acc.w += __shfl_xor(acc.w, 32);
    if (h == 0) {
        float dv = dinv[wid];
        float4 o = { acc.x * dv, acc.y * dv, acc.z * dv, acc.w * dv };
        ((float4*)agg1)[(size_t)wid * 32 + li] = o;
    }
}

// ---------------------------------------------------------------------------
// GEMM1 + bias + ReLU:  h1 = relu(agg1 @ W1 + b1)   64x64 tile, 4x4/thread
// ---------------------------------------------------------------------------
#define BM 64
#define BN 64
#define BK 16

__global__ __launch_bounds__(256) void gemm1_relu_k(const float* __restrict__ A,
                                                    const float* __restrict__ B,
                                                    const float* __restrict__ bias,
                                                    float* __restrict__ C,
                                                    int M_) {
    __shared__ float As[BK][BM + 4];
    __shared__ float Bs[BK][BN + 4];
    int m0 = blockIdx.x * BM;
    int n0 = blockIdx.y * BN;
    int tid = threadIdx.x;
    int tx = tid & 15, ty = tid >> 4;
    float acc[4][4] = {};

    for (int k0 = 0; k0 < F_IN; k0 += BK) {
        {
            int r = tid >> 2, kk = (tid & 3) * 4;
            int row = m0 + r; if (row >= M_) row = M_ - 1;
            float4 av = *reinterpret_cast<const float4*>(A + (size_t)row * F_IN + k0 + kk);
            As[kk + 0][r] = av.x; As[kk + 1][r] = av.y;
            As[kk + 2][r] = av.z; As[kk + 3][r] = av.w;
        }
        {
            int k = tid >> 4, nn = (tid & 15) * 4;
            float4 bv = *reinterpret_cast<const float4*>(B + (size_t)(k0 + k) * F_HID + n0 + nn);
            *reinterpret_cast<float4*>(&Bs[k][nn]) = bv;
        }
        __syncthreads();
        #pragma unroll
        for (int kk = 0; kk < BK; ++kk) {
            float4 a = *reinterpret_cast<const float4*>(&As[kk][ty * 4]);
            float4 b = *reinterpret_cast<const float4*>(&Bs[kk][tx * 4]);
            acc[0][0] += a.x * b.x; acc[0][1] += a.x * b.y; acc[0][2] += a.x * b.z; acc[0][3] += a.x * b.w;
            acc[1][0] += a.y * b.x; acc[1][1] += a.y * b.y; acc[1][2] += a.y * b.z; acc[1][3] += a.y * b.w;
            acc[2][0] += a.z * b.x; acc[2][1] += a.z * b.y; acc[2][2] += a.z * b.z; acc[2][3] += a.z * b.w;
            acc[3][0] += a.w * b.x; acc[3][1] += a.w * b.y; acc[3][2] += a.w * b.z; acc[3][3] += a.w * b.w;
        }
        __syncthreads();
    }
    #pragma unroll
    for (int i = 0; i < 4; ++i) {
        int row = m0 + ty * 4 + i;
        if (row < M_) {
            float4 bi = *reinterpret_cast<const float4*>(bias + n0 + tx * 4);
            float4 o;
            o.x = fmaxf(acc[i][0] + bi.x, 0.f);
            o.y = fmaxf(acc[i][1] + bi.y, 0.f);
            o.z = fmaxf(acc[i][2] + bi.z, 0.f);
            o.w = fmaxf(acc[i][3] + bi.w, 0.f);
            *reinterpret_cast<float4*>(C + (size_t)row * F_HID + n0 + tx * 4) = o;
        }
    }
}

// ---------------------------------------------------------------------------
// GEMM2: h2' = (h1 @ W2) * dinv[row]    (source-side norm folded in)
// ---------------------------------------------------------------------------
__global__ __launch_bounds__(256) void gemm2_k(const float* __restrict__ h1,
                                               const float* __restrict__ W2,
                                               const float* __restrict__ dinv,
                                               float* __restrict__ h2,
                                               int N) {
    __shared__ float w2s[F_HID * F_OUT];
    __shared__ float hs[16][F_HID + 4];
    int tid = threadIdx.x;
    const float4* wg = (const float4*)W2;
    float4* ws4 = (float4*)w2s;
    for (int i = tid; i < F_HID * F_OUT / 4; i += 256) ws4[i] = wg[i];
    int n0 = blockIdx.x * 16;
    const float4* hg = (const float4*)(h1 + (size_t)n0 * F_HID);
    for (int i = tid; i < 16 * F_HID / 4; i += 256) {
        int r = i >> 6, c = i & 63;
        *reinterpret_cast<float4*>(&hs[r][c * 4]) = hg[i];
    }
    __syncthreads();
    int ln = tid >> 4, j = tid & 15;
    float acc = 0.f;
    #pragma unroll 8
    for (int k = 0; k < F_HID; ++k) acc += hs[ln][k] * w2s[k * F_OUT + j];
    h2[(size_t)(n0 + ln) * F_OUT + j] = acc * dinv[n0 + ln];
}

// ---------------------------------------------------------------------------
// agg2 + bias + log_softmax:  out = logsm( dinv[d]*(sum h2'[s] + h2'[d]) + b2 )
// One wave per node; 16 edges in flight; NO per-edge dinv gather.
// ---------------------------------------------------------------------------
__global__ __launch_bounds__(256) void agg2_softmax_k(const float* __restrict__ h2,
                                                      const float* __restrict__ dinv,
                                                      const int* __restrict__ start,
                                                      const int* __restrict__ deg,
                                                      const int* __restrict__ csr_src,
                                                      const float* __restrict__ b2,
                                                      float* __restrict__ out,
                                                      int N) {
    int wid = (blockIdx.x * 256 + threadIdx.x) >> 6;
    if (wid >= N) return;
    int lane = threadIdx.x & 63;
    int g  = lane >> 2;
    int j4 = lane & 3;
    const float4* h4 = (const float4*)h2;

    float sw = (g == 0) ? 1.f : 0.f;
    float4 self = h4[(size_t)wid * 4 + j4];
    float4 acc = { self.x * sw, self.y * sw, self.z * sw, self.w * sw };

    int s0 = start[wid], cnt = deg[wid];
    for (int p = 0; p < cnt; p += 16) {
        int e = p + g;
        bool ok = e < cnt;
        int   s  = ok ? csr_src[s0 + e] : wid;
        float nm = ok ? 1.f : 0.f;
        float4 v = h4[(size_t)s * 4 + j4];
        acc.x = fmaf(v.x, nm, acc.x);
        acc.y = fmaf(v.y, nm, acc.y);
        acc.z = fmaf(v.z, nm, acc.z);
        acc.w = fmaf(v.w, nm, acc.w);
    }
    #pragma unroll
    for (int o = 4; o <= 32; o <<= 1) {
        acc.x += __shfl_xor(acc.x, o);
        acc.y += __shfl_xor(acc.y, o);
        acc.z += __shfl_xor(acc.z, o);
        acc.w += __shfl_xor(acc.w, o);
    }
    float dv = dinv[wid];
    float4 bb = ((const float4*)b2)[j4];
    acc.x = acc.x * dv + bb.x; acc.y = acc.y * dv + bb.y;
    acc.z = acc.z * dv + bb.z; acc.w = acc.w * dv + bb.w;

    float m = fmaxf(fmaxf(acc.x, acc.y), fmaxf(acc.z, acc.w));
    m = fmaxf(m, __shfl_xor(m, 1));
    m = fmaxf(m, __shfl_xor(m, 2));
    float es = expf(acc.x - m) + expf(acc.y - m) + expf(acc.z - m) + expf(acc.w - m);
    es += __shfl_xor(es, 1);
    es += __shfl_xor(es, 2);
    float lse = m + logf(es);

    if (g == 0) {
        float4 o4 = { acc.x - lse, acc.y - lse, acc.z - lse, acc.w - lse };
        ((float4*)out)[(size_t)wid * 4 + j4] = o4;
    }
}

// ---------------------------------------------------------------------------
extern "C" void kernel_launch(void* const* d_in, const int* in_sizes, int n_in,
                              void* d_out, int out_size, void* d_ws, size_t ws_size,
                              hipStream_t stream) {
    const float* x  = (const float*)d_in[0];
    const int*   ei = (const int*)d_in[1];
    const float* W1 = (const float*)d_in[2];
    const float* b1 = (const float*)d_in[3];
    const float* W2 = (const float*)d_in[4];
    const float* b2 = (const float*)d_in[5];
    float* out = (float*)d_out;

    const int N = in_sizes[0] / F_IN;
    const int E = in_sizes[1] / 2;
    const int nbuk = (N + 63) >> 6;
    const int cpe  = (E + NCH - 1) / NCH;

    auto align4k = [](size_t v) { return (v + 4095) & ~(size_t)4095; };
    char* ws = (char*)d_ws;
    size_t off = 0;
    int*   M      = (int*)(ws + off);  off += align4k((size_t)NCH * nbuk * 4);
    int*   totals = (int*)(ws + off);  off += align4k((size_t)nbuk * 4);
    int*   base   = (int*)(ws + off);  off += align4k((size_t)nbuk * 4);
    int*   deg    = (int*)(ws + off);  off += align4k((size_t)N * 4);
    int*   start  = (int*)(ws + off);  off += align4k((size_t)N * 4);
    float* dinv   = (float*)(ws + off); off += align4k((size_t)N * 4);
    int*   csr    = (int*)(ws + off);  off += align4k((size_t)E * 4);
    float* agg1   = (float*)(ws + off); off += align4k((size_t)N * F_IN * 4);
    // region R1 (size of h1 = N*F_HID*4): tmp pairs + xs live here early,
    // h1 overwrites them after both are dead.
    char*  R1     = ws + off;
    int2*  tmp    = (int2*)R1;
    float* xs     = (float*)(R1 + align4k((size_t)E * 8));
    float* h1     = (float*)R1;
    float* h2pre  = agg1;                 // agg1 dead after gemm1

    // ---- CSR build: no global atomics, no memset ----
    hist_k    <<<NCH, 256, 0, stream>>>(ei, M, E, cpe, nbuk);
    colscan_k <<<nbuk, 64, 0, stream>>>(M, totals, nbuk);
    base_k    <<<1, 1024, 0, stream>>>(totals, base, nbuk);
    bscatter_k<<<NCH, 256, 0, stream>>>(ei, M, base, tmp, E, cpe, nbuk);
    fin_k     <<<nbuk, 256, 0, stream>>>(tmp, base, totals, x, csr, start, deg,
                                         dinv, xs, N);

    // ---- layer 1: aggregate-first (F=128), then GEMM+ReLU ----
    agg1_k<<<(N + 3) / 4, 256, 0, stream>>>(xs, dinv, start, deg, csr, agg1, N);
    dim3 g1((N + BM - 1) / BM, F_HID / BN);
    gemm1_relu_k<<<g1, 256, 0, stream>>>(agg1, W1, b1, h1, N);

    // ---- layer 2: transform-first (F=16), fused norm + bias + log_softmax ----
    gemm2_k<<<N / 16, 256, 0, stream>>>(h1, W2, dinv, h2pre, N);
    agg2_softmax_k<<<(N + 3) / 4, 256, 0, stream>>>(h2pre, dinv, start, deg,
                                                    csr, b2, out, N);
}

// Round 9
// 421.437 us; speedup vs baseline: 1.4636x; 1.1335x over previous
//
#include <hip/hip_runtime.h>
#include <hip/hip_bf16.h>

#define F_IN   128
#define F_HID  256
#define F_OUT  16
#define NCH    256     // edge chunks (must stay 256: colscan_k assumes it)
#define MAXBUK 1600    // buckets of 64 dsts; supports N <= 102400

// ---- bf16 helpers (RNE pack, shift unpack) --------------------------------
__device__ inline unsigned short f2bf(float x) {
    unsigned int u = __float_as_uint(x);
    unsigned int r = (u + 0x7FFFu + ((u >> 16) & 1u)) >> 16;
    return (unsigned short)r;
}
__device__ inline unsigned int pack2(float lo, float hi) {
    return (unsigned int)f2bf(lo) | ((unsigned int)f2bf(hi) << 16);
}
__device__ inline void unpack8(uint4 v, float* f) {
    f[0] = __uint_as_float(v.x << 16); f[1] = __uint_as_float(v.x & 0xFFFF0000u);
    f[2] = __uint_as_float(v.y << 16); f[3] = __uint_as_float(v.y & 0xFFFF0000u);
    f[4] = __uint_as_float(v.z << 16); f[5] = __uint_as_float(v.z & 0xFFFF0000u);
    f[6] = __uint_as_float(v.w << 16); f[7] = __uint_as_float(v.w & 0xFFFF0000u);
}

// ---------------------------------------------------------------------------
// K1: per-chunk bucket histogram (LDS atomics only) -> M[chunk][bucket]
// ---------------------------------------------------------------------------
__global__ __launch_bounds__(256) void hist_k(const int* __restrict__ ei,
                                              int* __restrict__ M,
                                              int E, int cpe, int nbuk) {
    __shared__ int h[MAXBUK];
    int tid = threadIdx.x, blk = blockIdx.x;
    for (int b = tid; b < nbuk; b += 256) h[b] = 0;
    __syncthreads();
    int e0 = blk * cpe;
    for (int i = tid; i < cpe; i += 256) {
        int e = e0 + i;
        if (e < E) atomicAdd(&h[ei[E + e] >> 6], 1);
    }
    __syncthreads();
    for (int b = tid; b < nbuk; b += 256) M[(size_t)blk * nbuk + b] = h[b];
}

// ---------------------------------------------------------------------------
// K2: per-bucket exclusive scan over the 256 chunks (one wave per bucket)
// ---------------------------------------------------------------------------
__global__ __launch_bounds__(64) void colscan_k(int* __restrict__ M,
                                                int* __restrict__ totals,
                                                int nbuk) {
    int b = blockIdx.x, l = threadIdx.x;
    int v[4], s = 0;
    #pragma unroll
    for (int u = 0; u < 4; ++u) { v[u] = M[(size_t)(l * 4 + u) * nbuk + b]; s += v[u]; }
    int incl = s;
    #pragma unroll
    for (int o = 1; o < 64; o <<= 1) { int t = __shfl_up(incl, o); if (l >= o) incl += t; }
    int run = incl - s;
    #pragma unroll
    for (int u = 0; u < 4; ++u) { M[(size_t)(l * 4 + u) * nbuk + b] = run; run += v[u]; }
    if (l == 63) totals[b] = incl;
}

// ---------------------------------------------------------------------------
// K3: exclusive scan of bucket totals -> base[]
// ---------------------------------------------------------------------------
__global__ __launch_bounds__(1024) void base_k(const int* __restrict__ totals,
                                               int* __restrict__ base, int nbuk) {
    __shared__ int sm[1024];
    int t = threadIdx.x;
    int v0 = (2 * t     < nbuk) ? totals[2 * t]     : 0;
    int v1 = (2 * t + 1 < nbuk) ? totals[2 * t + 1] : 0;
    int p = v0 + v1;
    sm[t] = p;
    __syncthreads();
    for (int o = 1; o < 1024; o <<= 1) {
        int x = (t >= o) ? sm[t - o] : 0;
        __syncthreads();
        sm[t] += x;
        __syncthreads();
    }
    int excl = sm[t] - p;
    if (2 * t     < nbuk) base[2 * t]     = excl;
    if (2 * t + 1 < nbuk) base[2 * t + 1] = excl + v0;
}

// ---------------------------------------------------------------------------
// K4: scatter (src,dst) pairs into bucket regions; LDS cursors, no global atomics
// ---------------------------------------------------------------------------
__global__ __launch_bounds__(256) void bscatter_k(const int* __restrict__ ei,
                                                  const int* __restrict__ M,
                                                  const int* __restrict__ base,
                                                  int2* __restrict__ tmp,
                                                  int E, int cpe, int nbuk) {
    __shared__ int cur[MAXBUK];
    int tid = threadIdx.x, blk = blockIdx.x;
    for (int b = tid; b < nbuk; b += 256)
        cur[b] = base[b] + M[(size_t)blk * nbuk + b];
    __syncthreads();
    int e0 = blk * cpe;
    for (int i = tid; i < cpe; i += 256) {
        int e = e0 + i;
        if (e < E) {
            int s = ei[e], d = ei[E + e];
            int slot = atomicAdd(&cur[d >> 6], 1);     // LDS atomic
            tmp[slot] = make_int2(s, d);
        }
    }
}

// ---------------------------------------------------------------------------
// K5: finalize one bucket (64 dsts); emit deg/start/dinv; fused xs = bf16(x*dinv)
// ---------------------------------------------------------------------------
__global__ __launch_bounds__(256) void fin_k(const int2* __restrict__ tmp,
                                             const int* __restrict__ base,
                                             const int* __restrict__ totals,
                                             const float* __restrict__ x,
                                             int* __restrict__ csr_src,
                                             int* __restrict__ start,
                                             int* __restrict__ deg,
                                             float* __restrict__ dinv,
                                             uint4* __restrict__ xs,   // bf16 rows, 16B granules
                                             int N) {
    __shared__ int dcnt[64], dcur[64];
    __shared__ float sdv[64];
    int b = blockIdx.x, tid = threadIdx.x;
    int bb = base[b], cnt = totals[b];
    if (tid < 64) dcnt[tid] = 0;
    __syncthreads();
    for (int i = tid; i < cnt; i += 256)
        atomicAdd(&dcnt[tmp[bb + i].y & 63], 1);
    __syncthreads();
    if (tid < 64) {
        int l = tid, v = dcnt[l];
        int incl = v;
        #pragma unroll
        for (int o = 1; o < 64; o <<= 1) { int t2 = __shfl_up(incl, o); if (l >= o) incl += t2; }
        int excl = incl - v;
        dcur[l] = excl;
        float dv = rsqrtf((float)v + 1.f);
        sdv[l] = dv;
        int d = b * 64 + l;
        if (d < N) { deg[d] = v; start[d] = bb + excl; dinv[d] = dv; }
    }
    __syncthreads();
    for (int i = tid; i < cnt; i += 256) {
        int2 p = tmp[bb + i];
        int r = atomicAdd(&dcur[p.y & 63], 1);
        csr_src[bb + r] = p.x;
    }
    // fused: bf16 xs rows (128 bf16 = 16 uint4 per row)
    int d0 = b * 64;
    int nn = min(64, N - d0);
    const float4* x4 = (const float4*)x;
    for (int i = tid; i < nn * 16; i += 256) {
        int l = i >> 4, c = i & 15;
        float dv = sdv[l];
        size_t f4i = (size_t)(d0 + l) * 32 + c * 2;
        float4 a = x4[f4i], bq = x4[f4i + 1];
        a.x *= dv; a.y *= dv; a.z *= dv; a.w *= dv;
        bq.x *= dv; bq.y *= dv; bq.z *= dv; bq.w *= dv;
        uint4 o;
        o.x = pack2(a.x, a.y);  o.y = pack2(a.z, a.w);
        o.z = pack2(bq.x, bq.y); o.w = pack2(bq.z, bq.w);
        xs[(size_t)(d0 + l) * 16 + c] = o;
    }
}

// ---------------------------------------------------------------------------
// agg1 = dinv[d] * ( sum_{s} xs[s] + xs[d] ), xs in bf16 (256B rows), fp32 accum.
// One wave per dst; 16 lanes x 16B cover a row; 4 quarter-waves x 4 unroll
// -> 16 row-gathers in flight per wave. Half the bytes of the fp32 version.
// ---------------------------------------------------------------------------
__global__ __launch_bounds__(256) void agg1_k(const uint4* __restrict__ xs,
                                              const float* __restrict__ dinv,
                                              const int* __restrict__ start,
                                              const int* __restrict__ deg,
                                              const int* __restrict__ csr_src,
                                              float* __restrict__ agg1,
                                              int N) {
    int wid = (blockIdx.x * 256 + threadIdx.x) >> 6;
    if (wid >= N) return;
    int lane = threadIdx.x & 63;
    int q  = lane >> 4;      // edge slot within a group of 4
    int li = lane & 15;      // 16B granule within the 256B row

    float acc[8];
    {
        uint4 self = xs[(size_t)wid * 16 + li];
        float f[8]; unpack8(self, f);
        float sw = (q == 0) ? 1.f : 0.f;
        #pragma unroll
        for (int j = 0; j < 8; ++j) acc[j] = f[j] * sw;
    }

    int s0 = start[wid], cnt = deg[wid];
    for (int p = 0; p < cnt; p += 16) {
        int s[4]; float nm[4]; uint4 v[4];
        #pragma unroll
        for (int u = 0; u < 4; ++u) {
            int e = p + u * 4 + q;
            s[u]  = (e < cnt) ? csr_src[s0 + e] : wid;
            nm[u] = (e < cnt) ? 1.f : 0.f;
        }
        #pragma unroll
        for (int u = 0; u < 4; ++u)
            v[u] = xs[(size_t)s[u] * 16 + li];
        #pragma unroll
        for (int u = 0; u < 4; ++u) {
            float f[8]; unpack8(v[u], f);
            #pragma unroll
            for (int j = 0; j < 8; ++j) acc[j] = fmaf(f[j], nm[u], acc[j]);
        }
    }
    // combine the 4 quarter-waves (lane bits 4,5)
    #pragma unroll
    for (int j = 0; j < 8; ++j) {
        acc[j] += __shfl_xor(acc[j], 16);
        acc[j] += __shfl_xor(acc[j], 32);
    }
    if (q == 0) {
        float dv = dinv[wid];
        float4 o0 = { acc[0] * dv, acc[1] * dv, acc[2] * dv, acc[3] * dv };
        float4 o1 = { acc[4] * dv, acc[5] * dv, acc[6] * dv, acc[7] * dv };
        ((float4*)agg1)[(size_t)wid * 32 + li * 2 + 0] = o0;
        ((float4*)agg1)[(size_t)wid * 32 + li * 2 + 1] = o1;
    }
}

// ---------------------------------------------------------------------------
// GEMM1 + bias + ReLU:  h1 = relu(agg1 @ W1 + b1)   64x64 tile, 4x4/thread
// ---------------------------------------------------------------------------
#define BM 64
#define BN 64
#define BK 16

__global__ __launch_bounds__(256) void gemm1_relu_k(const float* __restrict__ A,
                                                    const float* __restrict__ B,
                                                    const float* __restrict__ bias,
                                                    float* __restrict__ C,
                                                    int M_) {
    __shared__ float As[BK][BM + 4];
    __shared__ float Bs[BK][BN + 4];
    int m0 = blockIdx.x * BM;
    int n0 = blockIdx.y * BN;
    int tid = threadIdx.x;
    int tx = tid & 15, ty = tid >> 4;
    float acc[4][4] = {};

    for (int k0 = 0; k0 < F_IN; k0 += BK) {
        {
            int r = tid >> 2, kk = (tid & 3) * 4;
            int row = m0 + r; if (row >= M_) row = M_ - 1;
            float4 av = *reinterpret_cast<const float4*>(A + (size_t)row * F_IN + k0 + kk);
            As[kk + 0][r] = av.x; As[kk + 1][r] = av.y;
            As[kk + 2][r] = av.z; As[kk + 3][r] = av.w;
        }
        {
            int k = tid >> 4, nn = (tid & 15) * 4;
            float4 bv = *reinterpret_cast<const float4*>(B + (size_t)(k0 + k) * F_HID + n0 + nn);
            *reinterpret_cast<float4*>(&Bs[k][nn]) = bv;
        }
        __syncthreads();
        #pragma unroll
        for (int kk = 0; kk < BK; ++kk) {
            float4 a = *reinterpret_cast<const float4*>(&As[kk][ty * 4]);
            float4 b = *reinterpret_cast<const float4*>(&Bs[kk][tx * 4]);
            acc[0][0] += a.x * b.x; acc[0][1] += a.x * b.y; acc[0][2] += a.x * b.z; acc[0][3] += a.x * b.w;
            acc[1][0] += a.y * b.x; acc[1][1] += a.y * b.y; acc[1][2] += a.y * b.z; acc[1][3] += a.y * b.w;
            acc[2][0] += a.z * b.x; acc[2][1] += a.z * b.y; acc[2][2] += a.z * b.z; acc[2][3] += a.z * b.w;
            acc[3][0] += a.w * b.x; acc[3][1] += a.w * b.y; acc[3][2] += a.w * b.z; acc[3][3] += a.w * b.w;
        }
        __syncthreads();
    }
    #pragma unroll
    for (int i = 0; i < 4; ++i) {
        int row = m0 + ty * 4 + i;
        if (row < M_) {
            float4 bi = *reinterpret_cast<const float4*>(bias + n0 + tx * 4);
            float4 o;
            o.x = fmaxf(acc[i][0] + bi.x, 0.f);
            o.y = fmaxf(acc[i][1] + bi.y, 0.f);
            o.z = fmaxf(acc[i][2] + bi.z, 0.f);
            o.w = fmaxf(acc[i][3] + bi.w, 0.f);
            *reinterpret_cast<float4*>(C + (size_t)row * F_HID + n0 + tx * 4) = o;
        }
    }
}

// ---------------------------------------------------------------------------
// GEMM2: h2' = (h1 @ W2) * dinv[row]
// ---------------------------------------------------------------------------
__global__ __launch_bounds__(256) void gemm2_k(const float* __restrict__ h1,
                                               const float* __restrict__ W2,
                                               const float* __restrict__ dinv,
                                               float* __restrict__ h2,
                                               int N) {
    __shared__ float w2s[F_HID * F_OUT];
    __shared__ float hs[16][F_HID + 4];
    int tid = threadIdx.x;
    const float4* wg = (const float4*)W2;
    float4* ws4 = (float4*)w2s;
    for (int i = tid; i < F_HID * F_OUT / 4; i += 256) ws4[i] = wg[i];
    int n0 = blockIdx.x * 16;
    const float4* hg = (const float4*)(h1 + (size_t)n0 * F_HID);
    for (int i = tid; i < 16 * F_HID / 4; i += 256) {
        int r = i >> 6, c = i & 63;
        *reinterpret_cast<float4*>(&hs[r][c * 4]) = hg[i];
    }
    __syncthreads();
    int ln = tid >> 4, j = tid & 15;
    float acc = 0.f;
    #pragma unroll 8
    for (int k = 0; k < F_HID; ++k) acc += hs[ln][k] * w2s[k * F_OUT + j];
    h2[(size_t)(n0 + ln) * F_OUT + j] = acc * dinv[n0 + ln];
}

// ---------------------------------------------------------------------------
// agg2 + bias + log_softmax
// ---------------------------------------------------------------------------
__global__ __launch_bounds__(256) void agg2_softmax_k(const float* __restrict__ h2,
                                                      const float* __restrict__ dinv,
                                                      const int* __restrict__ start,
                                                      const int* __restrict__ deg,
                                                      const int* __restrict__ csr_src,
                                                      const float* __restrict__ b2,
                                                      float* __restrict__ out,
                                                      int N) {
    int wid = (blockIdx.x * 256 + threadIdx.x) >> 6;
    if (wid >= N) return;
    int lane = threadIdx.x & 63;
    int g  = lane >> 2;
    int j4 = lane & 3;
    const float4* h4 = (const float4*)h2;

    float sw = (g == 0) ? 1.f : 0.f;
    float4 self = h4[(size_t)wid * 4 + j4];
    float4 acc = { self.x * sw, self.y * sw, self.z * sw, self.w * sw };

    int s0 = start[wid], cnt = deg[wid];
    for (int p = 0; p < cnt; p += 16) {
        int e = p + g;
        bool ok = e < cnt;
        int   s  = ok ? csr_src[s0 + e] : wid;
        float nm = ok ? 1.f : 0.f;
        float4 v = h4[(size_t)s * 4 + j4];
        acc.x = fmaf(v.x, nm, acc.x);
        acc.y = fmaf(v.y, nm, acc.y);
        acc.z = fmaf(v.z, nm, acc.z);
        acc.w = fmaf(v.w, nm, acc.w);
    }
    #pragma unroll
    for (int o = 4; o <= 32; o <<= 1) {
        acc.x += __shfl_xor(acc.x, o);
        acc.y += __shfl_xor(acc.y, o);
        acc.z += __shfl_xor(acc.z, o);
        acc.w += __shfl_xor(acc.w, o);
    }
    float dv = dinv[wid];
    float4 bb = ((const float4*)b2)[j4];
    acc.x = acc.x * dv + bb.x; acc.y = acc.y * dv + bb.y;
    acc.z = acc.z * dv + bb.z; acc.w = acc.w * dv + bb.w;

    float m = fmaxf(fmaxf(acc.x, acc.y), fmaxf(acc.z, acc.w));
    m = fmaxf(m, __shfl_xor(m, 1));
    m = fmaxf(m, __shfl_xor(m, 2));
    float es = expf(acc.x - m) + expf(acc.y - m) + expf(acc.z - m) + expf(acc.w - m);
    es += __shfl_xor(es, 1);
    es += __shfl_xor(es, 2);
    float lse = m + logf(es);

    if (g == 0) {
        float4 o4 = { acc.x - lse, acc.y - lse, acc.z - lse, acc.w - lse };
        ((float4*)out)[(size_t)wid * 4 + j4] = o4;
    }
}

// ---------------------------------------------------------------------------
extern "C" void kernel_launch(void* const* d_in, const int* in_sizes, int n_in,
                              void* d_out, int out_size, void* d_ws, size_t ws_size,
                              hipStream_t stream) {
    const float* x  = (const float*)d_in[0];
    const int*   ei = (const int*)d_in[1];
    const float* W1 = (const float*)d_in[2];
    const float* b1 = (const float*)d_in[3];
    const float* W2 = (const float*)d_in[4];
    const float* b2 = (const float*)d_in[5];
    float* out = (float*)d_out;

    const int N = in_sizes[0] / F_IN;
    const int E = in_sizes[1] / 2;
    const int nbuk = (N + 63) >> 6;
    const int cpe  = (E + NCH - 1) / NCH;

    auto align4k = [](size_t v) { return (v + 4095) & ~(size_t)4095; };
    char* ws = (char*)d_ws;
    size_t off = 0;
    int*   M      = (int*)(ws + off);  off += align4k((size_t)NCH * nbuk * 4);
    int*   totals = (int*)(ws + off);  off += align4k((size_t)nbuk * 4);
    int*   base   = (int*)(ws + off);  off += align4k((size_t)nbuk * 4);
    int*   deg    = (int*)(ws + off);  off += align4k((size_t)N * 4);
    int*   start  = (int*)(ws + off);  off += align4k((size_t)N * 4);
    float* dinv   = (float*)(ws + off); off += align4k((size_t)N * 4);
    int*   csr    = (int*)(ws + off);  off += align4k((size_t)E * 4);
    float* agg1   = (float*)(ws + off); off += align4k((size_t)N * F_IN * 4);
    // region R1 (size of h1 = N*F_HID*4): tmp pairs + xs(bf16) live here early,
    // h1 overwrites them after both are dead.
    char*  R1     = ws + off;
    int2*  tmp    = (int2*)R1;
    uint4* xs     = (uint4*)(R1 + align4k((size_t)E * 8));   // N*128*2 bytes
    float* h1     = (float*)R1;
    float* h2pre  = agg1;                 // agg1 dead after gemm1

    // ---- CSR build: no global atomics, no memset ----
    hist_k    <<<NCH, 256, 0, stream>>>(ei, M, E, cpe, nbuk);
    colscan_k <<<nbuk, 64, 0, stream>>>(M, totals, nbuk);
    base_k    <<<1, 1024, 0, stream>>>(totals, base, nbuk);
    bscatter_k<<<NCH, 256, 0, stream>>>(ei, M, base, tmp, E, cpe, nbuk);
    fin_k     <<<nbuk, 256, 0, stream>>>(tmp, base, totals, x, csr, start, deg,
                                         dinv, xs, N);

    // ---- layer 1: aggregate-first (F=128, bf16 gathers), then GEMM+ReLU ----
    agg1_k<<<(N + 3) / 4, 256, 0, stream>>>(xs, dinv, start, deg, csr, agg1, N);
    dim3 g1((N + BM - 1) / BM, F_HID / BN);
    gemm1_relu_k<<<g1, 256, 0, stream>>>(agg1, W1, b1, h1, N);

    // ---- layer 2: transform-first (F=16), fused norm + bias + log_softmax ----
    gemm2_k<<<N / 16, 256, 0, stream>>>(h1, W2, dinv, h2pre, N);
    agg2_softmax_k<<<(N + 3) / 4, 256, 0, stream>>>(h2pre, dinv, start, deg,
                                                    csr, b2, out, N);
}

// Round 14
// 344.656 us; speedup vs baseline: 1.7897x; 1.2228x over previous
//
#include <hip/hip_runtime.h>
#include <hip/hip_bf16.h>

#define F_IN   128
#define F_HID  256
#define F_OUT  16
#define NCH    256     // edge chunks (must stay 256: colscan_k assumes it)
#define MAXBUK 1600    // buckets of 64 dsts; supports N <= 102400

typedef float v4f __attribute__((ext_vector_type(4)));
typedef short v8s __attribute__((ext_vector_type(8)));

// ---- bf16 helpers (RNE pack, shift unpack) --------------------------------
__device__ inline unsigned short f2bf(float x) {
    unsigned int u = __float_as_uint(x);
    unsigned int r = (u + 0x7FFFu + ((u >> 16) & 1u)) >> 16;
    return (unsigned short)r;
}
__device__ inline unsigned int pack2(float lo, float hi) {
    return (unsigned int)f2bf(lo) | ((unsigned int)f2bf(hi) << 16);
}
__device__ inline void unpack8(uint4 v, float* f) {
    f[0] = __uint_as_float(v.x << 16); f[1] = __uint_as_float(v.x & 0xFFFF0000u);
    f[2] = __uint_as_float(v.y << 16); f[3] = __uint_as_float(v.y & 0xFFFF0000u);
    f[4] = __uint_as_float(v.z << 16); f[5] = __uint_as_float(v.z & 0xFFFF0000u);
    f[6] = __uint_as_float(v.w << 16); f[7] = __uint_as_float(v.w & 0xFFFF0000u);
}

// ---------------------------------------------------------------------------
// K1: per-chunk bucket histogram (LDS atomics only) -> M[chunk][bucket]
// ---------------------------------------------------------------------------
__global__ __launch_bounds__(256) void hist_k(const int* __restrict__ ei,
                                              int* __restrict__ M,
                                              int E, int cpe, int nbuk) {
    __shared__ int h[MAXBUK];
    int tid = threadIdx.x, blk = blockIdx.x;
    for (int b = tid; b < nbuk; b += 256) h[b] = 0;
    __syncthreads();
    int e0 = blk * cpe;
    for (int i = tid; i < cpe; i += 256) {
        int e = e0 + i;
        if (e < E) atomicAdd(&h[ei[E + e] >> 6], 1);
    }
    __syncthreads();
    for (int b = tid; b < nbuk; b += 256) M[(size_t)blk * nbuk + b] = h[b];
}

// ---------------------------------------------------------------------------
// K2: per-bucket exclusive scan over the 256 chunks (one wave per bucket)
// ---------------------------------------------------------------------------
__global__ __launch_bounds__(64) void colscan_k(int* __restrict__ M,
                                                int* __restrict__ totals,
                                                int nbuk) {
    int b = blockIdx.x, l = threadIdx.x;
    int v[4], s = 0;
    #pragma unroll
    for (int u = 0; u < 4; ++u) { v[u] = M[(size_t)(l * 4 + u) * nbuk + b]; s += v[u]; }
    int incl = s;
    #pragma unroll
    for (int o = 1; o < 64; o <<= 1) { int t = __shfl_up(incl, o); if (l >= o) incl += t; }
    int run = incl - s;
    #pragma unroll
    for (int u = 0; u < 4; ++u) { M[(size_t)(l * 4 + u) * nbuk + b] = run; run += v[u]; }
    if (l == 63) totals[b] = incl;
}

// ---------------------------------------------------------------------------
// K3: exclusive scan of bucket totals -> base[]
// ---------------------------------------------------------------------------
__global__ __launch_bounds__(1024) void base_k(const int* __restrict__ totals,
                                               int* __restrict__ base, int nbuk) {
    __shared__ int sm[1024];
    int t = threadIdx.x;
    int v0 = (2 * t     < nbuk) ? totals[2 * t]     : 0;
    int v1 = (2 * t + 1 < nbuk) ? totals[2 * t + 1] : 0;
    int p = v0 + v1;
    sm[t] = p;
    __syncthreads();
    for (int o = 1; o < 1024; o <<= 1) {
        int x = (t >= o) ? sm[t - o] : 0;
        __syncthreads();
        sm[t] += x;
        __syncthreads();
    }
    int excl = sm[t] - p;
    if (2 * t     < nbuk) base[2 * t]     = excl;
    if (2 * t + 1 < nbuk) base[2 * t + 1] = excl + v0;
}

// ---------------------------------------------------------------------------
// K4: scatter (src,dst) pairs into bucket regions; LDS cursors, no global atomics
// ---------------------------------------------------------------------------
__global__ __launch_bounds__(256) void bscatter_k(const int* __restrict__ ei,
                                                  const int* __restrict__ M,
                                                  const int* __restrict__ base,
                                                  int2* __restrict__ tmp,
                                                  int E, int cpe, int nbuk) {
    __shared__ int cur[MAXBUK];
    int tid = threadIdx.x, blk = blockIdx.x;
    for (int b = tid; b < nbuk; b += 256)
        cur[b] = base[b] + M[(size_t)blk * nbuk + b];
    __syncthreads();
    int e0 = blk * cpe;
    for (int i = tid; i < cpe; i += 256) {
        int e = e0 + i;
        if (e < E) {
            int s = ei[e], d = ei[E + e];
            int slot = atomicAdd(&cur[d >> 6], 1);     // LDS atomic
            tmp[slot] = make_int2(s, d);
        }
    }
}

// ---------------------------------------------------------------------------
// K5: finalize one bucket (64 dsts); emit deg/start/dinv; fused xs = bf16(x*dinv)
// ---------------------------------------------------------------------------
__global__ __launch_bounds__(256) void fin_k(const int2* __restrict__ tmp,
                                             const int* __restrict__ base,
                                             const int* __restrict__ totals,
                                             const float* __restrict__ x,
                                             int* __restrict__ csr_src,
                                             int* __restrict__ start,
                                             int* __restrict__ deg,
                                             float* __restrict__ dinv,
                                             uint4* __restrict__ xs,   // bf16 rows, 16B granules
                                             int N) {
    __shared__ int dcnt[64], dcur[64];
    __shared__ float sdv[64];
    int b = blockIdx.x, tid = threadIdx.x;
    int bb = base[b], cnt = totals[b];
    if (tid < 64) dcnt[tid] = 0;
    __syncthreads();
    for (int i = tid; i < cnt; i += 256)
        atomicAdd(&dcnt[tmp[bb + i].y & 63], 1);
    __syncthreads();
    if (tid < 64) {
        int l = tid, v = dcnt[l];
        int incl = v;
        #pragma unroll
        for (int o = 1; o < 64; o <<= 1) { int t2 = __shfl_up(incl, o); if (l >= o) incl += t2; }
        int excl = incl - v;
        dcur[l] = excl;
        float dv = rsqrtf((float)v + 1.f);
        sdv[l] = dv;
        int d = b * 64 + l;
        if (d < N) { deg[d] = v; start[d] = bb + excl; dinv[d] = dv; }
    }
    __syncthreads();
    for (int i = tid; i < cnt; i += 256) {
        int2 p = tmp[bb + i];
        int r = atomicAdd(&dcur[p.y & 63], 1);
        csr_src[bb + r] = p.x;
    }
    // fused: bf16 xs rows (128 bf16 = 16 uint4 per row)
    int d0 = b * 64;
    int nn = min(64, N - d0);
    const float4* x4 = (const float4*)x;
    for (int i = tid; i < nn * 16; i += 256) {
        int l = i >> 4, c = i & 15;
        float dv = sdv[l];
        size_t f4i = (size_t)(d0 + l) * 32 + c * 2;
        float4 a = x4[f4i], bq = x4[f4i + 1];
        a.x *= dv; a.y *= dv; a.z *= dv; a.w *= dv;
        bq.x *= dv; bq.y *= dv; bq.z *= dv; bq.w *= dv;
        uint4 o;
        o.x = pack2(a.x, a.y);  o.y = pack2(a.z, a.w);
        o.z = pack2(bq.x, bq.y); o.w = pack2(bq.z, bq.w);
        xs[(size_t)(d0 + l) * 16 + c] = o;
    }
}

// ---------------------------------------------------------------------------
// agg1 = dinv[d]*(sum xs[s] + xs[d]); bf16 gathers, fp32 accum, bf16 OUTPUT.
// ---------------------------------------------------------------------------
__global__ __launch_bounds__(256) void agg1_k(const uint4* __restrict__ xs,
                                              const float* __restrict__ dinv,
                                              const int* __restrict__ start,
                                              const int* __restrict__ deg,
                                              const int* __restrict__ csr_src,
                                              uint4* __restrict__ agg1bf,  // bf16 [N][128]
                                              int N) {
    int wid = (blockIdx.x * 256 + threadIdx.x) >> 6;
    if (wid >= N) return;
    int lane = threadIdx.x & 63;
    int q  = lane >> 4;      // edge slot within a group of 4
    int li = lane & 15;      // 16B granule within the 256B row

    float acc[8];
    {
        uint4 self = xs[(size_t)wid * 16 + li];
        float f[8]; unpack8(self, f);
        float sw = (q == 0) ? 1.f : 0.f;
        #pragma unroll
        for (int j = 0; j < 8; ++j) acc[j] = f[j] * sw;
    }

    int s0 = start[wid], cnt = deg[wid];
    for (int p = 0; p < cnt; p += 16) {
        int s[4]; float nm[4]; uint4 v[4];
        #pragma unroll
        for (int u = 0; u < 4; ++u) {
            int e = p + u * 4 + q;
            s[u]  = (e < cnt) ? csr_src[s0 + e] : wid;
            nm[u] = (e < cnt) ? 1.f : 0.f;
        }
        #pragma unroll
        for (int u = 0; u < 4; ++u)
            v[u] = xs[(size_t)s[u] * 16 + li];
        #pragma unroll
        for (int u = 0; u < 4; ++u) {
            float f[8]; unpack8(v[u], f);
            #pragma unroll
            for (int j = 0; j < 8; ++j) acc[j] = fmaf(f[j], nm[u], acc[j]);
        }
    }
    #pragma unroll
    for (int j = 0; j < 8; ++j) {
        acc[j] += __shfl_xor(acc[j], 16);
        acc[j] += __shfl_xor(acc[j], 32);
    }
    if (q == 0) {
        float dv = dinv[wid];
        uint4 o;
        o.x = pack2(acc[0] * dv, acc[1] * dv);
        o.y = pack2(acc[2] * dv, acc[3] * dv);
        o.z = pack2(acc[4] * dv, acc[5] * dv);
        o.w = pack2(acc[6] * dv, acc[7] * dv);
        agg1bf[(size_t)wid * 16 + li] = o;
    }
}

// ---------------------------------------------------------------------------
// GEMM1 via MFMA bf16: h1 = bf16(relu(agg1bf @ W1 + b1))
// Block = 256 thr = 4 waves; M-tile = 256 rows (64/wave); N = 256 full.
// W1 staged to LDS as bf16 W1^T[n][k], XOR-granule swizzle (64 KB exactly).
// A-frag: lane holds A[row = rt*16 + (l&15)][k = kt*32 + (l>>4)*8 .. +8].
// C/D (m89-verified): col = l&15, row = (l>>4)*4 + reg.
// ---------------------------------------------------------------------------
__global__ __launch_bounds__(256) void gemm1_mfma_k(
        const unsigned short* __restrict__ A,   // agg1bf [N][128] bf16
        const float* __restrict__ W1,           // [128][256] fp32
        const float* __restrict__ b1,
        unsigned short* __restrict__ h1,        // [N][256] bf16
        int N_) {
    __shared__ unsigned short w1t[256 * 128];   // 64 KB, swizzled [n][k]
    int tid = threadIdx.x;

    // stage W1^T -> bf16 LDS; granule g (16B=8 elems) swizzled by g ^= (n&15)
    for (int i = tid; i < 64 * 256; i += 256) {
        int kk = i >> 8;            // 0..63
        int n  = i & 255;
        int k2 = kk << 1;           // even k
        float w0 = W1[(size_t)k2 * 256 + n];
        float w1v = W1[(size_t)(k2 + 1) * 256 + n];
        int g = k2 >> 3;
        unsigned int byteoff = (unsigned)n * 256u + ((unsigned)(g ^ (n & 15)) << 4) + ((unsigned)(k2 & 7) << 1);
        *(unsigned int*)((char*)w1t + byteoff) = pack2(w0, w1v);
    }
    __syncthreads();

    int w  = tid >> 6, l = tid & 63;
    int lr = l & 15, kc = l >> 4;
    int m0 = blockIdx.x * 256 + w * 64;

    // A fragments: a[rt][kt], 16 x 16B = 64 VGPR
    v8s a[4][4];
    #pragma unroll
    for (int rt = 0; rt < 4; ++rt) {
        int row = m0 + rt * 16 + lr;
        if (row >= N_) row = N_ - 1;
        const unsigned short* ap = A + (size_t)row * 128 + kc * 8;
        #pragma unroll
        for (int kt = 0; kt < 4; ++kt)
            a[rt][kt] = *(const v8s*)(ap + kt * 32);
    }

    for (int nt = 0; nt < 16; ++nt) {
        // B frags for this n-tile: n = nt*16 + lr, granule g = kt*4 + kc, swz g^lr
        const char* wb = (const char*)w1t + (unsigned)(nt * 16 + lr) * 256u;
        v8s b0 = *(const v8s*)(wb + (((0 * 4 + kc) ^ lr) << 4));
        v8s bb1 = *(const v8s*)(wb + (((1 * 4 + kc) ^ lr) << 4));
        v8s b2 = *(const v8s*)(wb + (((2 * 4 + kc) ^ lr) << 4));
        v8s b3 = *(const v8s*)(wb + (((3 * 4 + kc) ^ lr) << 4));
        float bias = b1[nt * 16 + lr];
        int colg = nt * 16 + lr;
        #pragma unroll
        for (int rt = 0; rt < 4; ++rt) {
            v4f acc = {0.f, 0.f, 0.f, 0.f};
            acc = __builtin_amdgcn_mfma_f32_16x16x32_bf16(a[rt][0], b0,  acc, 0, 0, 0);
            acc = __builtin_amdgcn_mfma_f32_16x16x32_bf16(a[rt][1], bb1, acc, 0, 0, 0);
            acc = __builtin_amdgcn_mfma_f32_16x16x32_bf16(a[rt][2], b2,  acc, 0, 0, 0);
            acc = __builtin_amdgcn_mfma_f32_16x16x32_bf16(a[rt][3], b3,  acc, 0, 0, 0);
            #pragma unroll
            for (int r = 0; r < 4; ++r) {
                int row = m0 + rt * 16 + kc * 4 + r;
                if (row < N_) {
                    float vv = fmaxf(acc[r] + bias, 0.f);
                    h1[(size_t)row * 256 + colg] = f2bf(vv);
                }
            }
        }
    }
}

// ---------------------------------------------------------------------------
// GEMM2: h2' = (h1bf @ W2) * dinv[row]   (h1 in bf16; fp32 compute)
// ---------------------------------------------------------------------------
__global__ __launch_bounds__(256) void gemm2_k(const unsigned short* __restrict__ h1,
                                               const float* __restrict__ W2,
                                               const float* __restrict__ dinv,
                                               float* __restrict__ h2,
                                               int N) {
    __shared__ float w2s[F_HID * F_OUT];      // 16 KB
    __shared__ float hs[16][F_HID + 4];
    int tid = threadIdx.x;
    const float4* wg = (const float4*)W2;
    float4* ws4 = (float4*)w2s;
    for (int i = tid; i < F_HID * F_OUT / 4; i += 256) ws4[i] = wg[i];
    int n0 = blockIdx.x * 16;
    const uint4* hg = (const uint4*)(h1 + (size_t)n0 * F_HID);
    for (int i = tid; i < 512; i += 256) {        // 16 rows x 32 granules(8 bf16)
        int r = i >> 5, c = i & 31;
        float f[8]; unpack8(hg[i], f);
        #pragma unroll
        for (int j = 0; j < 8; ++j) hs[r][c * 8 + j] = f[j];
    }
    __syncthreads();
    int ln = tid >> 4, j = tid & 15;
    float acc = 0.f;
    #pragma unroll 8
    for (int k = 0; k < F_HID; ++k) acc += hs[ln][k] * w2s[k * F_OUT + j];
    h2[(size_t)(n0 + ln) * F_OUT + j] = acc * dinv[n0 + ln];
}

// ---------------------------------------------------------------------------
// agg2 + bias + log_softmax
// ---------------------------------------------------------------------------
__global__ __launch_bounds__(256) void agg2_softmax_k(const float* __restrict__ h2,
                                                      const float* __restrict__ dinv,
                                                      const int* __restrict__ start,
                                                      const int* __restrict__ deg,
                                                      const int* __restrict__ csr_src,
                                                      const float* __restrict__ b2,
                                                      float* __restrict__ out,
                                                      int N) {
    int wid = (blockIdx.x * 256 + threadIdx.x) >> 6;
    if (wid >= N) return;
    int lane = threadIdx.x & 63;
    int g  = lane >> 2;
    int j4 = lane & 3;
    const float4* h4 = (const float4*)h2;

    float sw = (g == 0) ? 1.f : 0.f;
    float4 self = h4[(size_t)wid * 4 + j4];
    float4 acc = { self.x * sw, self.y * sw, self.z * sw, self.w * sw };

    int s0 = start[wid], cnt = deg[wid];
    for (int p = 0; p < cnt; p += 16) {
        int e = p + g;
        bool ok = e < cnt;
        int   s  = ok ? csr_src[s0 + e] : wid;
        float nm = ok ? 1.f : 0.f;
        float4 v = h4[(size_t)s * 4 + j4];
        acc.x = fmaf(v.x, nm, acc.x);
        acc.y = fmaf(v.y, nm, acc.y);
        acc.z = fmaf(v.z, nm, acc.z);
        acc.w = fmaf(v.w, nm, acc.w);
    }
    #pragma unroll
    for (int o = 4; o <= 32; o <<= 1) {
        acc.x += __shfl_xor(acc.x, o);
        acc.y += __shfl_xor(acc.y, o);
        acc.z += __shfl_xor(acc.z, o);
        acc.w += __shfl_xor(acc.w, o);
    }
    float dv = dinv[wid];
    float4 bb = ((const float4*)b2)[j4];
    acc.x = acc.x * dv + bb.x; acc.y = acc.y * dv + bb.y;
    acc.z = acc.z * dv + bb.z; acc.w = acc.w * dv + bb.w;

    float m = fmaxf(fmaxf(acc.x, acc.y), fmaxf(acc.z, acc.w));
    m = fmaxf(m, __shfl_xor(m, 1));
    m = fmaxf(m, __shfl_xor(m, 2));
    float es = expf(acc.x - m) + expf(acc.y - m) + expf(acc.z - m) + expf(acc.w - m);
    es += __shfl_xor(es, 1);
    es += __shfl_xor(es, 2);
    float lse = m + logf(es);

    if (g == 0) {
        float4 o4 = { acc.x - lse, acc.y - lse, acc.z - lse, acc.w - lse };
        ((float4*)out)[(size_t)wid * 4 + j4] = o4;
    }
}

// ---------------------------------------------------------------------------
extern "C" void kernel_launch(void* const* d_in, const int* in_sizes, int n_in,
                              void* d_out, int out_size, void* d_ws, size_t ws_size,
                              hipStream_t stream) {
    const float* x  = (const float*)d_in[0];
    const int*   ei = (const int*)d_in[1];
    const float* W1 = (const float*)d_in[2];
    const float* b1 = (const float*)d_in[3];
    const float* W2 = (const float*)d_in[4];
    const float* b2 = (const float*)d_in[5];
    float* out = (float*)d_out;

    const int N = in_sizes[0] / F_IN;
    const int E = in_sizes[1] / 2;
    const int nbuk = (N + 63) >> 6;
    const int cpe  = (E + NCH - 1) / NCH;

    auto align4k = [](size_t v) { return (v + 4095) & ~(size_t)4095; };
    char* ws = (char*)d_ws;
    size_t off = 0;
    int*   M      = (int*)(ws + off);  off += align4k((size_t)NCH * nbuk * 4);
    int*   totals = (int*)(ws + off);  off += align4k((size_t)nbuk * 4);
    int*   base   = (int*)(ws + off);  off += align4k((size_t)nbuk * 4);
    int*   deg    = (int*)(ws + off);  off += align4k((size_t)N * 4);
    int*   start  = (int*)(ws + off);  off += align4k((size_t)N * 4);
    float* dinv   = (float*)(ws + off); off += align4k((size_t)N * 4);
    int*   csr    = (int*)(ws + off);  off += align4k((size_t)E * 4);
    // agg1 slot (sized for N*128*4): holds agg1bf (bf16, half used), later h2pre
    char*  aggslot = ws + off;          off += align4k((size_t)N * F_IN * 4);
    uint4* agg1bf = (uint4*)aggslot;
    float* h2pre  = (float*)aggslot;    // agg1bf dead after gemm1
    // region R1 (sized N*F_HID*4): tmp + xs early; h1(bf16) after both dead
    char*  R1     = ws + off;
    int2*  tmp    = (int2*)R1;
    uint4* xs     = (uint4*)(R1 + align4k((size_t)E * 8));   // N*256 B
    unsigned short* h1 = (unsigned short*)R1;                // N*256*2 B

    // ---- CSR build: no global atomics, no memset ----
    hist_k    <<<NCH, 256, 0, stream>>>(ei, M, E, cpe, nbuk);
    colscan_k <<<nbuk, 64, 0, stream>>>(M, totals, nbuk);
    base_k    <<<1, 1024, 0, stream>>>(totals, base, nbuk);
    bscatter_k<<<NCH, 256, 0, stream>>>(ei, M, base, tmp, E, cpe, nbuk);
    fin_k     <<<nbuk, 256, 0, stream>>>(tmp, base, totals, x, csr, start, deg,
                                         dinv, xs, N);

    // ---- layer 1: aggregate-first (bf16 gathers) -> MFMA GEMM + bias + ReLU ----
    agg1_k<<<(N + 3) / 4, 256, 0, stream>>>(xs, dinv, start, deg, csr, agg1bf, N);
    gemm1_mfma_k<<<(N + 255) / 256, 256, 0, stream>>>(
        (const unsigned short*)agg1bf, W1, b1, h1, N);

    // ---- layer 2: transform-first (F=16), fused norm + bias + log_softmax ----
    gemm2_k<<<N / 16, 256, 0, stream>>>(h1, W2, dinv, h2pre, N);
    agg2_softmax_k<<<(N + 3) / 4, 256, 0, stream>>>(h2pre, dinv, start, deg,
                                                    csr, b2, out, N);
}